// Round 8
// baseline (71.619 us; speedup 1.0000x reference)
//
#include <hip/hip_runtime.h>

#define NATOMS 13
#define NP (NATOMS * NATOMS)   // 169

constexpr int N_ = 1024;   // rows
constexpr int H_ = 512;    // inner dim
constexpr int O_ = 512;    // output dim
constexpr int RB = 8;      // rows per W stream (oct)
constexpr int OSPLIT = 4;
constexpr int OC = O_ / OSPLIT;        // 128 cols per panel
constexpr int MAXOCT = 276;            // >= sum ceil(c_g/8) worst case
constexpr int NB = MAXOCT * OSPLIT;    // 1104 blocks (div by 8)
constexpr int RECS = 12;   // ints per oct record: rows[8], id, pad

// ws ints: [0] nocts; records at ws+16: [oct*RECS + {0..7}] rows, [+8] id
// ------------------------------------------------------------------ build octs
__global__ void build_octs(const int* __restrict__ x,
                           const int* __restrict__ fact,
                           int* __restrict__ ws, int N) {
    __shared__ int s_id[N_];
    __shared__ int s_cnt[NP];
    __shared__ int s_start[NP];
    __shared__ int s_ostart[NP];
    __shared__ int s_pos[NP];
    __shared__ int s_sorted[N_];
    const int tid = threadIdx.x, bd = blockDim.x;

    for (int i = tid; i < NP; i += bd) { s_cnt[i] = 0; s_pos[i] = 0; }
    __syncthreads();
    for (int n = tid; n < N; n += bd) {
        const int f0 = fact[2 * n];
        const int id = x[f0 * 3 + 1] * NATOMS + x[f0 * 3 + 2];
        s_id[n] = id;
        atomicAdd(&s_cnt[id], 1);
    }
    __syncthreads();
    if (tid == 0) {
        int run = 0, orun = 0;
        for (int g = 0; g < NP; ++g) {
            s_start[g] = run;   run  += s_cnt[g];
            s_ostart[g] = orun; orun += (s_cnt[g] + RB - 1) / RB;
        }
        ws[0] = orun;  // nocts
    }
    __syncthreads();
    for (int n = tid; n < N; n += bd) {
        const int id = s_id[n];
        const int p = atomicAdd(&s_pos[id], 1);
        s_sorted[s_start[id] + p] = n;
    }
    __syncthreads();
    for (int g = tid; g < NP; g += bd) {
        const int c = s_cnt[g], st = s_start[g], os = s_ostart[g];
        const int no = (c + RB - 1) / RB;
        for (int k = 0; k < no; ++k) {
            int* rec = ws + 16 + (size_t)(os + k) * RECS;
            for (int r = 0; r < RB; ++r) {
                const int idx = k * RB + r;
                rec[r] = (idx < c) ? s_sorted[st + idx] : -1;
            }
            rec[RB] = g;
        }
    }
}

// ------------------------------------------------------------------- oct GEMV
// One block per (oct, o-panel). Streams W[id][0:512, o0:o0+128] once with an
// explicit 8-deep static ping-pong pipeline (R7 pattern); each 16B W load
// feeds 32 FMAs (8 rows x 4 cols). 4-way h-split across thread sub-groups,
// one LDS reduce at the end, bias, direct float4 stores. No atomics/memset.
__global__ __launch_bounds__(128)
void oct_gemv(const int* __restrict__ ws,
              const float* __restrict__ inp,
              const float* __restrict__ params,
              const float* __restrict__ bias,
              const int* __restrict__ msg_to_p,
              const int* __restrict__ order_p,
              float* __restrict__ out, int N) {
    // bijective XCD-chunked swizzle (NB % 8 == 0): panels of an oct and
    // neighboring octs (same group -> same W) share an XCD for L2 reuse.
    constexpr int q = NB / 8;
    const int b = blockIdx.x;
    const int Lg = (b & 7) * q + (b >> 3);
    const int oct = Lg >> 2;
    const int op  = Lg & 3;

    if (oct >= ws[0]) return;
    const int* rec = ws + 16 + (size_t)oct * RECS;
    const int id = rec[RB];

    const int msg_to = *msg_to_p;
    const int order  = *order_p;
    const int tid = threadIdx.x;
    const int sub = tid >> 5;        // 0..3: h-row within each 4-row step
    const int l   = tid & 31;        // col-quad within panel
    const int o0  = op * OC;

    __shared__ float  fp_s[H_][RB];      // 16 KB, [h][r]
    __shared__ float4 red[4][RB][32];    // 16 KB, [sub][r][l]

    // stage fact_prod for all H, all 8 rows (coalesced 512B per (r,k,factor))
#pragma unroll
    for (int r = 0; r < RB; ++r) {
        const int row = rec[r];
        if (row >= 0) {
#pragma unroll
            for (int k = 0; k < H_ / 128; ++k) {
                const int h = k * 128 + tid;
                float p = 1.0f;
                for (int i = 0; i < order; ++i)
                    if (i != msg_to)
                        p *= inp[((size_t)i * N + row) * H_ + h];
                fp_s[h][r] = p;
            }
        } else {
#pragma unroll
            for (int k = 0; k < H_ / 128; ++k) fp_s[k * 128 + tid][r] = 0.0f;
        }
    }
    __syncthreads();

    const float* __restrict__ wbase =
        params + (size_t)id * H_ * O_ + (size_t)sub * O_ + o0 + 4 * l;

    float4 a0 = make_float4(0,0,0,0), a1 = a0, a2 = a0, a3 = a0;
    float4 a4 = a0, a5 = a0, a6 = a0, a7 = a0;

#define LOADW(W, hb)                                                  \
    W[0] = *(const float4*)(wbase + (size_t)((hb) +  0) * O_);        \
    W[1] = *(const float4*)(wbase + (size_t)((hb) +  4) * O_);        \
    W[2] = *(const float4*)(wbase + (size_t)((hb) +  8) * O_);        \
    W[3] = *(const float4*)(wbase + (size_t)((hb) + 12) * O_);        \
    W[4] = *(const float4*)(wbase + (size_t)((hb) + 16) * O_);        \
    W[5] = *(const float4*)(wbase + (size_t)((hb) + 20) * O_);        \
    W[6] = *(const float4*)(wbase + (size_t)((hb) + 24) * O_);        \
    W[7] = *(const float4*)(wbase + (size_t)((hb) + 28) * O_);

#define FMA4(acc, s, wv) acc.x += (s) * wv.x; acc.y += (s) * wv.y;    \
                         acc.z += (s) * wv.z; acc.w += (s) * wv.w;

#define CONS1(wv, h)                                                  \
    { const float4 fA = *(const float4*)&fp_s[(h) + sub][0];          \
      const float4 fB = *(const float4*)&fp_s[(h) + sub][4];          \
      FMA4(a0, fA.x, wv) FMA4(a1, fA.y, wv)                           \
      FMA4(a2, fA.z, wv) FMA4(a3, fA.w, wv)                           \
      FMA4(a4, fB.x, wv) FMA4(a5, fB.y, wv)                           \
      FMA4(a6, fB.z, wv) FMA4(a7, fB.w, wv) }

#define CONSUME(W, hb)                                                \
    CONS1(W[0], (hb) +  0) CONS1(W[1], (hb) +  4)                     \
    CONS1(W[2], (hb) +  8) CONS1(W[3], (hb) + 12)                     \
    CONS1(W[4], (hb) + 16) CONS1(W[5], (hb) + 20)                     \
    CONS1(W[6], (hb) + 24) CONS1(W[7], (hb) + 28)

    float4 wA[8], wB[8];
    LOADW(wA, 0)
#pragma unroll
    for (int hb = 0; hb < H_; hb += 64) {
        LOADW(wB, hb + 32)         // next 8 in flight while consuming wA
        CONSUME(wA, hb)
        if (hb + 64 < H_) { LOADW(wA, hb + 64) }
        CONSUME(wB, hb + 32)
    }
#undef LOADW
#undef FMA4
#undef CONS1
#undef CONSUME

    // cross-subgroup reduce (once per block)
    red[sub][0][l] = a0; red[sub][1][l] = a1;
    red[sub][2][l] = a2; red[sub][3][l] = a3;
    red[sub][4][l] = a4; red[sub][5][l] = a5;
    red[sub][6][l] = a6; red[sub][7][l] = a7;
    __syncthreads();

    const float4 bv = *(const float4*)(bias + (size_t)id * O_ + o0 + 4 * l);

    // thread (sub, l) emits rows sub and sub+4 (static 2-step)
#define EMIT(rr)                                                      \
    { const int row = rec[rr];                                        \
      if (row >= 0) {                                                 \
          const float4 p0 = red[0][rr][l];                            \
          const float4 p1 = red[1][rr][l];                            \
          const float4 p2 = red[2][rr][l];                            \
          const float4 p3 = red[3][rr][l];                            \
          float4 s;                                                   \
          s.x = p0.x + p1.x + p2.x + p3.x + bv.x;                     \
          s.y = p0.y + p1.y + p2.y + p3.y + bv.y;                     \
          s.z = p0.z + p1.z + p2.z + p3.z + bv.z;                     \
          s.w = p0.w + p1.w + p2.w + p3.w + bv.w;                     \
          *(float4*)(out + (size_t)row * O_ + o0 + 4 * l) = s;        \
      } }
    EMIT(sub)
    EMIT(sub + 4)
#undef EMIT
}

// ---------------------------------------------------------------------- launch
extern "C" void kernel_launch(void* const* d_in, const int* in_sizes, int n_in,
                              void* d_out, int out_size, void* d_ws, size_t ws_size,
                              hipStream_t stream) {
    const int*   x      = (const int*)d_in[0];
    const int*   fact   = (const int*)d_in[1];
    const float* inp    = (const float*)d_in[2];
    const float* params = (const float*)d_in[3];
    const float* bias   = (const float*)d_in[4];
    const int*   msg_to = (const int*)d_in[5];
    const int*   order  = (const int*)d_in[6];
    float*       out    = (float*)d_out;

    const int N = in_sizes[1] / 2;   // 1024
    int* ws = (int*)d_ws;

    hipLaunchKernelGGL(build_octs, dim3(1), dim3(256), 0, stream,
                       x, fact, ws, N);

    hipLaunchKernelGGL(oct_gemv, dim3(NB), dim3(128), 0, stream,
                       ws, inp, params, bias, msg_to, order, out, N);
}

// Round 9
// 51.574 us; speedup vs baseline: 1.3887x; 1.3887x over previous
//
#include <hip/hip_runtime.h>

#define NATOMS 13
#define NP (NATOMS * NATOMS)   // 169

constexpr int N_ = 1024;   // rows
constexpr int H_ = 512;    // inner dim
constexpr int O_ = 512;    // output dim
constexpr int RB = 2;      // rows per W stream (pair) — R3's proven shape
constexpr int OSPLIT = 2;
constexpr int OC = O_ / OSPLIT;        // 256 cols per panel
constexpr int MAXPAIR = 600;           // >= sum ceil(c_g/2) worst case (596)
constexpr int NB = MAXPAIR * OSPLIT;   // 1200 blocks (div by 8)
constexpr int RECS = 4;    // ints per pair record: row0, row1, id, pad

// ws ints: [0] npairs; records at ws+16: [pair*RECS] = {row0, row1(-1 ok), id}
// ----------------------------------------------------------------- build pairs
__global__ void build_pairs(const int* __restrict__ x,
                            const int* __restrict__ fact,
                            int* __restrict__ ws, int N) {
    __shared__ int s_id[N_];
    __shared__ int s_cnt[NP];
    __shared__ int s_start[NP];
    __shared__ int s_pstart[NP];
    __shared__ int s_pos[NP];
    __shared__ int s_sorted[N_];
    const int tid = threadIdx.x, bd = blockDim.x;

    for (int i = tid; i < NP; i += bd) { s_cnt[i] = 0; s_pos[i] = 0; }
    __syncthreads();
    for (int n = tid; n < N; n += bd) {
        const int f0 = fact[2 * n];
        const int id = x[f0 * 3 + 1] * NATOMS + x[f0 * 3 + 2];
        s_id[n] = id;
        atomicAdd(&s_cnt[id], 1);
    }
    __syncthreads();
    if (tid == 0) {
        int run = 0, prun = 0;
        for (int g = 0; g < NP; ++g) {
            s_start[g] = run;   run  += s_cnt[g];
            s_pstart[g] = prun; prun += (s_cnt[g] + 1) >> 1;
        }
        ws[0] = prun;  // npairs
    }
    __syncthreads();
    for (int n = tid; n < N; n += bd) {
        const int id = s_id[n];
        const int p = atomicAdd(&s_pos[id], 1);
        s_sorted[s_start[id] + p] = n;
    }
    __syncthreads();
    for (int g = tid; g < NP; g += bd) {
        const int c = s_cnt[g], st = s_start[g], ps = s_pstart[g];
        for (int k = 0; k < c; k += 2) {
            int* rec = ws + 16 + (size_t)(ps + (k >> 1)) * RECS;
            rec[0] = s_sorted[st + k];
            rec[1] = (k + 1 < c) ? s_sorted[st + k + 1] : -1;
            rec[2] = g;
        }
    }
}

// ------------------------------------------------------------------ pair GEMV
// One block per (pair, o-panel). 128 threads: sub=tid>>6 (2-way h-split),
// l=tid&63 (col-quad in 256-col panel). Streams W[id][:, o0:o0+256] once:
// per h, one float4 load + one fp_s float2 broadcast + 8 FMAs (R3 intensity).
// End: one LDS reduce across the 2 sub-groups, bias, direct float4 store.
// No atomics, no memset.
__global__ __launch_bounds__(128)
void pair_gemv(const int* __restrict__ ws,
               const float* __restrict__ inp,
               const float* __restrict__ params,
               const float* __restrict__ bias,
               const int* __restrict__ msg_to_p,
               const int* __restrict__ order_p,
               float* __restrict__ out, int N) {
    // bijective XCD-chunked swizzle (NB % 8 == 0): the 2 panels of a pair and
    // neighboring pairs (same group -> same W) share an XCD for L2 reuse.
    constexpr int q = NB / 8;
    const int b = blockIdx.x;
    const int Lg = (b & 7) * q + (b >> 3);
    const int pair = Lg >> 1;
    const int op   = Lg & 1;

    if (pair >= ws[0]) return;
    const int* rec = ws + 16 + (size_t)pair * RECS;
    const int row0 = rec[0];
    const int row1 = rec[1];
    const int id   = rec[2];

    const int msg_to = *msg_to_p;
    const int order  = *order_p;
    const int tid = threadIdx.x;
    const int sub = tid >> 6;        // 0..1: h parity
    const int l   = tid & 63;        // col-quad within panel
    const int o0  = op * OC;

    __shared__ float  fp_s[H_][RB];      // 4 KB, [h][r]
    __shared__ float4 red[2][RB][64];    // 4 KB, [sub][r][l]

    // stage fact_prod for all H, both rows (coalesced 512B per (r,k,factor))
#pragma unroll
    for (int k = 0; k < H_ / 128; ++k) {
        const int h = k * 128 + tid;
        float p0 = 1.0f, p1 = 0.0f;
        for (int i = 0; i < order; ++i)
            if (i != msg_to)
                p0 *= inp[((size_t)i * N + row0) * H_ + h];
        if (row1 >= 0) {
            p1 = 1.0f;
            for (int i = 0; i < order; ++i)
                if (i != msg_to)
                    p1 *= inp[((size_t)i * N + row1) * H_ + h];
        }
        fp_s[h][0] = p0;
        fp_s[h][1] = p1;
    }
    __syncthreads();

    // h-rows for this sub: h = 2*hh + sub, hh in [0, 256)
    const float* __restrict__ wbase =
        params + (size_t)id * H_ * O_ + (size_t)sub * O_ + o0 + 4 * l;

    float4 a0 = make_float4(0,0,0,0), a1 = a0;

#define FMA4(acc, s, wv) acc.x += (s) * wv.x; acc.y += (s) * wv.y;    \
                         acc.z += (s) * wv.z; acc.w += (s) * wv.w;
#pragma unroll 8
    for (int hh = 0; hh < H_ / 2; ++hh) {
        const float4 w = *(const float4*)(wbase + (size_t)hh * 2 * O_);
        const float2 f = *(const float2*)&fp_s[2 * hh + sub][0];
        FMA4(a0, f.x, w)
        FMA4(a1, f.y, w)
    }
#undef FMA4

    red[sub][0][l] = a0;
    red[sub][1][l] = a1;
    __syncthreads();

    // thread (sub, l) emits row rec[sub], cols o0 + 4l
    const int row = (sub == 0) ? row0 : row1;
    if (row >= 0) {
        const float4 p0 = red[0][sub][l];
        const float4 p1 = red[1][sub][l];
        const float4 bv = *(const float4*)(bias + (size_t)id * O_ + o0 + 4 * l);
        float4 s;
        s.x = p0.x + p1.x + bv.x;
        s.y = p0.y + p1.y + bv.y;
        s.z = p0.z + p1.z + bv.z;
        s.w = p0.w + p1.w + bv.w;
        *(float4*)(out + (size_t)row * O_ + o0 + 4 * l) = s;
    }
}

// ---------------------------------------------------------------------- launch
extern "C" void kernel_launch(void* const* d_in, const int* in_sizes, int n_in,
                              void* d_out, int out_size, void* d_ws, size_t ws_size,
                              hipStream_t stream) {
    const int*   x      = (const int*)d_in[0];
    const int*   fact   = (const int*)d_in[1];
    const float* inp    = (const float*)d_in[2];
    const float* params = (const float*)d_in[3];
    const float* bias   = (const float*)d_in[4];
    const int*   msg_to = (const int*)d_in[5];
    const int*   order  = (const int*)d_in[6];
    float*       out    = (float*)d_out;

    const int N = in_sizes[1] / 2;   // 1024
    int* ws = (int*)d_ws;

    hipLaunchKernelGGL(build_pairs, dim3(1), dim3(256), 0, stream,
                       x, fact, ws, N);

    hipLaunchKernelGGL(pair_gemv, dim3(NB), dim3(128), 0, stream,
                       ws, inp, params, bias, msg_to, order, out, N);
}

// Round 10
// 51.521 us; speedup vs baseline: 1.3901x; 1.0010x over previous
//
#include <hip/hip_runtime.h>

#define NATOMS 13
#define NP (NATOMS * NATOMS)   // 169

constexpr int N_ = 1024;   // rows
constexpr int H_ = 512;    // inner dim
constexpr int O_ = 512;    // output dim
constexpr int RB = 4;      // rows per W stream (quad)
constexpr int OSPLIT = 2;
constexpr int OC = O_ / OSPLIT;        // 256 cols per panel (1KB contiguous)
constexpr int MAXQUAD = 384;           // >= sum ceil(c_g/4) (<=382)
constexpr int NB = MAXQUAD * OSPLIT;   // 768 blocks (div by 8)
constexpr int RECS = 8;    // ints per quad record: rows[4], id, pad

// ws ints: [0] nquads; records at ws+16: [quad*RECS + {0..3}] rows, [+4] id
// ----------------------------------------------------------------- build quads
__global__ void build_quads(const int* __restrict__ x,
                            const int* __restrict__ fact,
                            int* __restrict__ ws, int N) {
    __shared__ int s_id[N_];
    __shared__ int s_cnt[NP];
    __shared__ int s_start[NP];
    __shared__ int s_qstart[NP];
    __shared__ int s_pos[NP];
    __shared__ int s_sorted[N_];
    const int tid = threadIdx.x, bd = blockDim.x;

    for (int i = tid; i < NP; i += bd) { s_cnt[i] = 0; s_pos[i] = 0; }
    __syncthreads();
    for (int n = tid; n < N; n += bd) {
        const int f0 = fact[2 * n];
        const int id = x[f0 * 3 + 1] * NATOMS + x[f0 * 3 + 2];
        s_id[n] = id;
        atomicAdd(&s_cnt[id], 1);
    }
    __syncthreads();
    if (tid == 0) {
        int run = 0, qrun = 0;
        for (int g = 0; g < NP; ++g) {
            s_start[g] = run;   run  += s_cnt[g];
            s_qstart[g] = qrun; qrun += (s_cnt[g] + RB - 1) / RB;
        }
        ws[0] = qrun;  // nquads
    }
    __syncthreads();
    for (int n = tid; n < N; n += bd) {
        const int id = s_id[n];
        const int p = atomicAdd(&s_pos[id], 1);
        s_sorted[s_start[id] + p] = n;
    }
    __syncthreads();
    for (int g = tid; g < NP; g += bd) {
        const int c = s_cnt[g], st = s_start[g], qs = s_qstart[g];
        const int nq = (c + RB - 1) / RB;
        for (int k = 0; k < nq; ++k) {
            int* rec = ws + 16 + (size_t)(qs + k) * RECS;
            for (int r = 0; r < RB; ++r) {
                const int idx = k * RB + r;
                rec[r] = (idx < c) ? s_sorted[st + idx] : -1;
            }
            rec[RB] = g;
        }
    }
}

// ------------------------------------------------------------------ quad GEMV
// One block per (quad, o-panel), 256 threads (4 waves). sub=tid>>6 in {0..3}
// is the h-phase (h = 4*hh + sub), l=tid&63 is the col-quad in the 256-col
// panel. Per h: ONE float4 W load (1KB contiguous per wave) + one b128
// broadcast of fp_s + 16 FMAs. Compact unroll-8 body (~160 instrs, I$-safe).
// End: LDS reduce across 4 sub-phases, bias, direct float4 store. No atomics.
__global__ __launch_bounds__(256)
void quad_gemv(const int* __restrict__ ws,
               const float* __restrict__ inp,
               const float* __restrict__ params,
               const float* __restrict__ bias,
               const int* __restrict__ msg_to_p,
               const int* __restrict__ order_p,
               float* __restrict__ out, int N) {
    // bijective XCD-chunked swizzle (NB % 8 == 0): the 2 o-panels of a quad
    // and neighboring quads (same group -> same W) share an XCD.
    constexpr int q = NB / 8;
    const int b = blockIdx.x;
    const int Lg = (b & 7) * q + (b >> 3);
    const int quad = Lg >> 1;
    const int op   = Lg & 1;

    if (quad >= ws[0]) return;
    const int* rec = ws + 16 + (size_t)quad * RECS;
    const int id = rec[RB];

    const int msg_to = *msg_to_p;
    const int order  = *order_p;
    const int tid = threadIdx.x;
    const int sub = tid >> 6;        // 0..3: h-phase
    const int l   = tid & 63;        // col-quad within 256-col panel
    const int o0  = op * OC;

    __shared__ float  fp_s[H_][RB];      // 8 KB, [h][r]
    __shared__ float4 red[4][RB][64];    // 16 KB, [sub][r][l]

    // stage fact_prod for all H, 4 rows (1KB contiguous per wave per load)
#pragma unroll
    for (int r = 0; r < RB; ++r) {
        const int row = rec[r];
        if (row >= 0) {
#pragma unroll
            for (int k = 0; k < H_ / 256; ++k) {
                const int h = k * 256 + tid;
                float p = 1.0f;
                for (int i = 0; i < order; ++i)
                    if (i != msg_to)
                        p *= inp[((size_t)i * N + row) * H_ + h];
                fp_s[h][r] = p;
            }
        } else {
#pragma unroll
            for (int k = 0; k < H_ / 256; ++k) fp_s[k * 256 + tid][r] = 0.0f;
        }
    }
    __syncthreads();

    // h-rows for this sub: h = 4*hh + sub, hh in [0, 128)
    const float* __restrict__ wbase =
        params + (size_t)id * H_ * O_ + (size_t)sub * O_ + o0 + 4 * l;

    float4 a0 = make_float4(0,0,0,0), a1 = a0, a2 = a0, a3 = a0;

#define FMA4(acc, s, wv) acc.x += (s) * wv.x; acc.y += (s) * wv.y;    \
                         acc.z += (s) * wv.z; acc.w += (s) * wv.w;
#pragma unroll 8
    for (int hh = 0; hh < H_ / 4; ++hh) {
        const float4 w = *(const float4*)(wbase + (size_t)hh * 4 * O_);
        const float4 f = *(const float4*)&fp_s[4 * hh + sub][0];
        FMA4(a0, f.x, w)
        FMA4(a1, f.y, w)
        FMA4(a2, f.z, w)
        FMA4(a3, f.w, w)
    }
#undef FMA4

    red[sub][0][l] = a0;
    red[sub][1][l] = a1;
    red[sub][2][l] = a2;
    red[sub][3][l] = a3;
    __syncthreads();

    // thread (sub, l) emits row rec[sub], cols o0 + 4l
    const int row = rec[sub];
    if (row >= 0) {
        const float4 p0 = red[0][sub][l];
        const float4 p1 = red[1][sub][l];
        const float4 p2 = red[2][sub][l];
        const float4 p3 = red[3][sub][l];
        const float4 bv = *(const float4*)(bias + (size_t)id * O_ + o0 + 4 * l);
        float4 s;
        s.x = p0.x + p1.x + p2.x + p3.x + bv.x;
        s.y = p0.y + p1.y + p2.y + p3.y + bv.y;
        s.z = p0.z + p1.z + p2.z + p3.z + bv.z;
        s.w = p0.w + p1.w + p2.w + p3.w + bv.w;
        *(float4*)(out + (size_t)row * O_ + o0 + 4 * l) = s;
    }
}

// ---------------------------------------------------------------------- launch
extern "C" void kernel_launch(void* const* d_in, const int* in_sizes, int n_in,
                              void* d_out, int out_size, void* d_ws, size_t ws_size,
                              hipStream_t stream) {
    const int*   x      = (const int*)d_in[0];
    const int*   fact   = (const int*)d_in[1];
    const float* inp    = (const float*)d_in[2];
    const float* params = (const float*)d_in[3];
    const float* bias   = (const float*)d_in[4];
    const int*   msg_to = (const int*)d_in[5];
    const int*   order  = (const int*)d_in[6];
    float*       out    = (float*)d_out;

    const int N = in_sizes[1] / 2;   // 1024
    int* ws = (int*)d_ws;

    hipLaunchKernelGGL(build_quads, dim3(1), dim3(256), 0, stream,
                       x, fact, ws, N);

    hipLaunchKernelGGL(quad_gemv, dim3(NB), dim3(256), 0, stream,
                       ws, inp, params, bias, msg_to, order, out, N);
}